// Round 1
// baseline (202.896 us; speedup 1.0000x reference)
//
#include <hip/hip_runtime.h>
#include <math.h>

#define BB 2
#define NN 4096
#define DIM 768
#define QSTRIDE 20  // 8 (q head0) + 8 (q head1) + w0 + w1 + 2 pad, float4-aligned

// ---------------------------------------------------------------------------
// qproj: qw = query_tokens @ Wq  (8192 rows x 768 -> 18 cols)
// One wave handles 2 rows. Lane-parallel over the 768 dim, butterfly reduce.
// Output layout per row (stride 20): [q0(8), q1(8), w0, w1, pad(2)]
//   qw cols: head0 q = 0..7, head0 w = 8, head1 q = 9..16, head1 w = 17
// ---------------------------------------------------------------------------
__global__ __launch_bounds__(256) void qproj_kernel(const float* __restrict__ x,
                                                    const float* __restrict__ Wq,
                                                    float* __restrict__ qd) {
  const int lane = threadIdx.x & 63;
  const int pair = blockIdx.x * 4 + (threadIdx.x >> 6);
  const int row0 = pair * 2;
  const float* xr0 = x + (size_t)row0 * DIM;
  const float* xr1 = xr0 + DIM;

  float acc0[18], acc1[18];
#pragma unroll
  for (int c = 0; c < 18; ++c) { acc0[c] = 0.f; acc1[c] = 0.f; }

#pragma unroll
  for (int j = 0; j < DIM / 64; ++j) {
    const int i = lane + 64 * j;
    const float x0 = xr0[i];
    const float x1 = xr1[i];
    const float* wr = Wq + i * 18;
#pragma unroll
    for (int c = 0; c < 9; ++c) {
      const float2 w2 = *(const float2*)(wr + 2 * c);
      acc0[2 * c]     = fmaf(x0, w2.x, acc0[2 * c]);
      acc0[2 * c + 1] = fmaf(x0, w2.y, acc0[2 * c + 1]);
      acc1[2 * c]     = fmaf(x1, w2.x, acc1[2 * c]);
      acc1[2 * c + 1] = fmaf(x1, w2.y, acc1[2 * c + 1]);
    }
  }

#pragma unroll
  for (int off = 32; off >= 1; off >>= 1) {
#pragma unroll
    for (int c = 0; c < 18; ++c) {
      acc0[c] += __shfl_xor(acc0[c], off, 64);
      acc1[c] += __shfl_xor(acc1[c], off, 64);
    }
  }

  // lanes 0..17 write row0, lanes 32..49 write row1 (all lanes hold full sums)
  const int r = lane >> 5;
  const int l = lane & 31;
  if (l < 18) {
    // dst slot l maps to qw column:
    //   l<8 -> col l ; 8<=l<16 -> col l+1 ; l==16 -> col 8 ; l==17 -> col 17
    int src;
    if (l < 8) src = l;
    else if (l < 16) src = l + 1;
    else if (l == 16) src = 8;
    else src = 17;
    float v = r ? acc1[0] : acc0[0];
#pragma unroll
    for (int c = 1; c < 18; ++c) {
      const float cand = r ? acc1[c] : acc0[c];
      v = (src == c) ? cand : v;
    }
    qd[(size_t)(row0 + r) * QSTRIDE + l] = v;
  }
}

// ---------------------------------------------------------------------------
// kproj: k = key_tokens @ Wk (8192 x 768 -> 8) + 2D sinusoidal PE
// pe[n] = [sin(y*h), cos(y*h), sin(y*.01h), cos(y*.01h),
//          sin(x*w), cos(x*w), sin(x*.01w), cos(x*.01w)]
//   y = (n/w_) / max(h-1,1), x = (n%w_) / max(w_-1,1); freqs = [1, 0.01]
// ---------------------------------------------------------------------------
__global__ __launch_bounds__(256) void kproj_kernel(const float* __restrict__ x,
                                                    const float* __restrict__ Wk,
                                                    const int* __restrict__ hp,
                                                    const int* __restrict__ wp,
                                                    float* __restrict__ kd) {
  const int lane = threadIdx.x & 63;
  const int pair = blockIdx.x * 4 + (threadIdx.x >> 6);
  const int row0 = pair * 2;
  const float* xr0 = x + (size_t)row0 * DIM;
  const float* xr1 = xr0 + DIM;

  float acc0[8], acc1[8];
#pragma unroll
  for (int c = 0; c < 8; ++c) { acc0[c] = 0.f; acc1[c] = 0.f; }

#pragma unroll
  for (int j = 0; j < DIM / 64; ++j) {
    const int i = lane + 64 * j;
    const float x0 = xr0[i];
    const float x1 = xr1[i];
    const float4 wa = *(const float4*)(Wk + i * 8);
    const float4 wb = *(const float4*)(Wk + i * 8 + 4);
    acc0[0] = fmaf(x0, wa.x, acc0[0]); acc0[1] = fmaf(x0, wa.y, acc0[1]);
    acc0[2] = fmaf(x0, wa.z, acc0[2]); acc0[3] = fmaf(x0, wa.w, acc0[3]);
    acc0[4] = fmaf(x0, wb.x, acc0[4]); acc0[5] = fmaf(x0, wb.y, acc0[5]);
    acc0[6] = fmaf(x0, wb.z, acc0[6]); acc0[7] = fmaf(x0, wb.w, acc0[7]);
    acc1[0] = fmaf(x1, wa.x, acc1[0]); acc1[1] = fmaf(x1, wa.y, acc1[1]);
    acc1[2] = fmaf(x1, wa.z, acc1[2]); acc1[3] = fmaf(x1, wa.w, acc1[3]);
    acc1[4] = fmaf(x1, wb.x, acc1[4]); acc1[5] = fmaf(x1, wb.y, acc1[5]);
    acc1[6] = fmaf(x1, wb.z, acc1[6]); acc1[7] = fmaf(x1, wb.w, acc1[7]);
  }

#pragma unroll
  for (int off = 32; off >= 1; off >>= 1) {
#pragma unroll
    for (int c = 0; c < 8; ++c) {
      acc0[c] += __shfl_xor(acc0[c], off, 64);
      acc1[c] += __shfl_xor(acc1[c], off, 64);
    }
  }

  const int r = lane >> 5;
  const int l = lane & 31;
  if (l < 8) {
    const int row = row0 + r;
    const int h = hp[0];
    const int w = wp[0];
    const int n = row % NN;
    const int yi = n / w;
    const int xi = n - yi * w;
    const int hd = (h - 1) > 1 ? (h - 1) : 1;
    const int wd = (w - 1) > 1 ? (w - 1) : 1;
    const float yv = (float)yi / (float)hd;
    const float xv = (float)xi / (float)wd;
    const float base = (l < 4) ? yv : xv;
    const float sc = (l < 4) ? (float)h : (float)w;
    const float fr = (l & 2) ? 0.01f : 1.0f;
    const float ang = base * fr * sc;
    const float pe = (l & 1) ? cosf(ang) : sinf(ang);
    float v = r ? acc1[0] : acc0[0];
#pragma unroll
    for (int c = 1; c < 8; ++c) {
      const float cand = r ? acc1[c] : acc0[c];
      v = (l == c) ? cand : v;
    }
    kd[(size_t)row * 8 + l] = v + pe;
  }
}

// ---------------------------------------------------------------------------
// scores: out[b,q,k] = w0*relu(scale*<q0,k>) + w1*relu(scale*<q1,k>) + bias
// Block: 256 threads; tile 32 queries x 64 keys.
// k tile in LDS, stride 9 (padded: 2-way bank aliasing only, free on CDNA4).
// q tile in LDS, stride 20 (float4-aligned b128 reads, bank-spread by ty).
// Thread (tx=tid&15, ty=tid>>4): 2 queries x 4 keys -> 2 float4 stores.
// ---------------------------------------------------------------------------
__device__ __forceinline__ float dot8(const float4 a, const float4 b,
                                      const float* __restrict__ k8) {
  float d = a.x * k8[0];
  d = fmaf(a.y, k8[1], d);
  d = fmaf(a.z, k8[2], d);
  d = fmaf(a.w, k8[3], d);
  d = fmaf(b.x, k8[4], d);
  d = fmaf(b.y, k8[5], d);
  d = fmaf(b.z, k8[6], d);
  d = fmaf(b.w, k8[7], d);
  return d;
}

__global__ __launch_bounds__(256) void scores_kernel(const float* __restrict__ qd,
                                                     const float* __restrict__ kd,
                                                     const float* __restrict__ bias,
                                                     float* __restrict__ out) {
  __shared__ float ks[64 * 9];
  __shared__ float qs[32 * QSTRIDE];

  const int tid = threadIdx.x;
  const int kb = blockIdx.x;  // 64-key tile
  const int qb = blockIdx.y;  // 32-query tile
  const int b  = blockIdx.z;

  // stage k tile: 64 keys x 8 floats = 128 float4 loads, scatter to stride 9
  if (tid < 128) {
    const float4 v = ((const float4*)(kd + ((size_t)b * NN + kb * 64) * 8))[tid];
    const int key = tid >> 1;
    const int off = (tid & 1) * 4;
    float* dst = ks + key * 9 + off;
    dst[0] = v.x; dst[1] = v.y; dst[2] = v.z; dst[3] = v.w;
  }
  // stage q tile: 32 queries x 20 floats = 160 float4 loads, contiguous
  if (tid < 160) {
    ((float4*)qs)[tid] = ((const float4*)(qd + ((size_t)b * NN + qb * 32) * QSTRIDE))[tid];
  }
  __syncthreads();

  const int tx = tid & 15;
  const int ty = tid >> 4;
  const float sb = bias[0];
  const float scale = 0.35355339059327373f;  // 8^-0.5

  const int k0 = tx * 4;
  float kv[4][8];
#pragma unroll
  for (int i = 0; i < 4; ++i) {
    const float* kp = ks + (k0 + i) * 9;
#pragma unroll
    for (int d = 0; d < 8; ++d) kv[i][d] = kp[d];
  }

#pragma unroll
  for (int qi = 0; qi < 2; ++qi) {
    const int lq = ty * 2 + qi;
    const float* qp = qs + lq * QSTRIDE;
    const float4 a0 = *(const float4*)(qp);
    const float4 a1 = *(const float4*)(qp + 4);
    const float4 b0 = *(const float4*)(qp + 8);
    const float4 b1 = *(const float4*)(qp + 12);
    const float w0 = qp[16];
    const float w1 = qp[17];

    float4 res;
    float* r = (float*)&res;
#pragma unroll
    for (int i = 0; i < 4; ++i) {
      float d0 = dot8(a0, a1, kv[i]);
      float d1 = dot8(b0, b1, kv[i]);
      d0 = fmaxf(d0 * scale, 0.f);
      d1 = fmaxf(d1 * scale, 0.f);
      r[i] = fmaf(w0, d0, fmaf(w1, d1, sb));
    }

    const int q = qb * 32 + lq;
    float* op = out + ((size_t)b * NN + q) * (size_t)NN + (size_t)(kb * 64 + k0);
    *(float4*)op = res;
  }
}

// ---------------------------------------------------------------------------
extern "C" void kernel_launch(void* const* d_in, const int* in_sizes, int n_in,
                              void* d_out, int out_size, void* d_ws, size_t ws_size,
                              hipStream_t stream) {
  const float* qt = (const float*)d_in[0];  // (2, 4096, 768)
  const float* kt = (const float*)d_in[1];  // (2, 4096, 768)
  const float* Wq = (const float*)d_in[2];  // (768, 18)
  const float* Wk = (const float*)d_in[3];  // (768, 8)
  const float* sb = (const float*)d_in[4];  // (1,1,1)
  const int* hp = (const int*)d_in[5];      // height (64)
  const int* wp = (const int*)d_in[6];      // width  (64)

  float* qd = (float*)d_ws;                      // 8192 * 20 floats = 640 KB
  float* kd = qd + (size_t)BB * NN * QSTRIDE;    // 8192 * 8 floats  = 256 KB
  float* outp = (float*)d_out;                   // (2, 4096, 4096) fp32

  // 8192 rows, 2 rows per wave, 4 waves per block -> 1024 blocks
  qproj_kernel<<<BB * NN / 8, 256, 0, stream>>>(qt, Wq, qd);
  kproj_kernel<<<BB * NN / 8, 256, 0, stream>>>(kt, Wk, hp, wp, kd);
  // 64 key-tiles x 128 query-tiles x 2 batches
  scores_kernel<<<dim3(64, NN / 32, BB), 256, 0, stream>>>(qd, kd, sb, outp);
}